// Round 6
// baseline (28.468 us; speedup 1.0000x reference)
//
#include <hip/hip_runtime.h>
#include <math.h>

#define N 256
#define H 128
#define E 64
#define K 4
#define M (N + 1)
#define WAVES 16
#define BLOCK 1024

// ---------------------------------------------------------------------------
// helpers
// ---------------------------------------------------------------------------
__device__ __forceinline__ float sigm(float x) {
    return __fdividef(1.0f, 1.0f + __expf(-x));
}

__device__ __forceinline__ float wave_sum(float v) {
#pragma unroll
    for (int d = 1; d < 64; d <<= 1) v += __shfl_xor(v, d, 64);
    return v;
}

__device__ __forceinline__ float readlane_f(float v, int l) {
    return __uint_as_float(__builtin_amdgcn_readlane(__float_as_uint(v), l));
}

// full k-transposed butterfly: lane l ends with wave_sum(q_{l&3})
__device__ __forceinline__ float kbutterfly(float q0, float q1, float q2, float q3,
                                            int lane) {
    const bool b1 = lane & 1;
    const bool b2 = lane & 2;
    float aA = b1 ? q1 : q0, aB = b1 ? q0 : q1;
    aA += __shfl_xor(aB, 1, 64);
    float cA = b1 ? q3 : q2, cB = b1 ? q2 : q3;
    cA += __shfl_xor(cB, 1, 64);
    float eA = b2 ? cA : aA, eB = b2 ? aA : cA;
    eA += __shfl_xor(eB, 2, 64);
#pragma unroll
    for (int d = 4; d < 64; d <<= 1) eA += __shfl_xor(eA, d, 64);
    return eA;
}

// Bit-exact replication of cal_dist's per-pair math (numpy fp32, no FMA
// contraction). Roles: r = row idx, c = col idx, r < c. Returns d[r][c], d[c][r].
__device__ __forceinline__ void pairdist(
    float a1x, float a1y, float a2x, float a2y,
    float g1x, float g1y, float g2x, float g2y,
    float baseR, float baseC, float& d_rc, float& d_cr)
{
    float t  = __fmul_rn(__fsub_rn(a1y, a2y), __fsub_rn(g1x, g2x));
    float dn = -t;  // (a1x-a1x)*(...) == 0 exactly
    float ca = __fsub_rn(__fmul_rn(a1x, a2y), __fmul_rn(a1y, a2x));
    float gt = __fsub_rn(__fmul_rn(g1x, g2y), __fmul_rn(g1x, g2x));  // ref bug kept
    float n1 = __fsub_rn(__fmul_rn(ca, __fsub_rn(g1x, g2x)),
                         __fmul_rn(__fsub_rn(a1x, a2x), gt));
    float n2 = __fsub_rn(__fmul_rn(ca, __fsub_rn(g1y, g2y)),
                         __fmul_rn(__fsub_rn(a1y, a2x), gt));        // ref bug kept
    float safe = (dn == 0.0f) ? 1.0f : dn;
    float p1 = __fdiv_rn(n1, safe);
    float p2 = __fdiv_rn(n2, safe);
    bool cond = (dn != 0.0f) &&
                (__fmul_rn(__fsub_rn(a1x, p1), __fsub_rn(p1, g1x)) > 0.0f);
    float dx1 = __fsub_rn(a1x, p1), dy1 = __fsub_rn(a1y, p2);
    float d1p = __fsqrt_rn(__fadd_rn(__fmul_rn(dx1, dx1), __fmul_rn(dy1, dy1)));
    float dx2 = __fsub_rn(a2x, p1), dy2 = __fsub_rn(a2y, p2);
    float d2p = __fsqrt_rn(__fadd_rn(__fmul_rn(dx2, dx2), __fmul_rn(dy2, dy2)));
    d_rc = cond ? d1p : baseR;
    d_cr = cond ? d2p : baseC;
}

// ---------------------------------------------------------------------------
// Kernel 1: precompute (unchanged), 256 blocks x 1024 threads
// ---------------------------------------------------------------------------
__global__ __launch_bounds__(BLOCK) void gat_pre(
    const float* __restrict__ ha, const float* __restrict__ hg,
    const float* __restrict__ W_emb, const float* __restrict__ b_emb,
    const float* __restrict__ W_gate, const float* __restrict__ b_gate,
    const float* __restrict__ W_gat, const float* __restrict__ a_src,
    const float* __restrict__ a_dst,
    float* __restrict__ A1, float* __restrict__ A2, float* __restrict__ G2,
    float* __restrict__ u3g, float* __restrict__ u4g, float* __restrict__ ccg,
    float* __restrict__ vsrc, float* __restrict__ vdst)
{
    const int b    = blockIdx.x;
    const int tid  = threadIdx.x;
    const int wid  = tid >> 6;
    const int lane = tid & 63;

    __shared__ float sRed[8][3][H];

    {
        const int f  = tid & (H - 1);
        const int sl = tid >> 7;
        const int g0 = sl * 16;
        float s1 = 0.f, s2 = 0.f, s3 = 0.f;
#pragma unroll
        for (int g = 0; g < 16; ++g) {
            const int gg = g0 + g;
            float w1 = W_gate[gg * H + f];
            float w2 = W_gate[(H + gg) * H + f];
            float av = ha[b * H + gg];
            float gv = hg[b * H + gg];
            s1 += av * w1;
            s2 += av * w2;
            s3 += gv * w2;
        }
        sRed[sl][0][f] = s1;
        sRed[sl][1][f] = s2;
        sRed[sl][2][f] = s3;
    }
    __syncthreads();
    if (tid < H) {
        float r1 = 0.f, r2 = 0.f, r3 = 0.f;
#pragma unroll
        for (int sl = 0; sl < 8; ++sl) {
            r1 += sRed[sl][0][tid];
            r2 += sRed[sl][1][tid];
            r3 += sRed[sl][2][tid];
        }
        A1[b * H + tid] = r1;
        A2[b * H + tid] = r2;
        G2[b * H + tid] = r3;
    }

    if (b < 8) {
        const int k = b >> 1;
        const float2 as = *(const float2*)&a_src[k * H + lane * 2];
        const float2 ad = *(const float2*)&a_dst[k * H + lane * 2];
#pragma unroll
        for (int it = 0; it < 4; ++it) {
            const int pair = b * 64 + wid * 4 + it;
            const int f    = pair & (H - 1);
            const float2 w = *(const float2*)&W_gat[(k * H + f) * H + lane * 2];
            float vs = wave_sum(w.x * as.x + w.y * as.y);
            float vv = wave_sum(w.x * ad.x + w.y * ad.y);
            if (lane == 0) { vsrc[k * H + f] = vs; vdst[k * H + f] = vv; }
        }
    } else if (b == 8) {
        __syncthreads();
        const int f  = tid & (H - 1);
        const int sl = tid >> 7;
        float s3 = 0.f, s4 = 0.f, scc = 0.f;
#pragma unroll
        for (int e0 = 0; e0 < 8; ++e0) {
            const int e = sl * 8 + e0;
            float w3 = W_gate[(2 * H + e) * H + f];
            float w4 = W_gate[(2 * H + E + e) * H + f];
            float we = W_emb[e], be = b_emb[e];
            s3  += we * w3;
            s4  += we * w4;
            scc += be * (w3 + w4);
        }
        sRed[sl][0][f] = s3;
        sRed[sl][1][f] = s4;
        sRed[sl][2][f] = scc;
        __syncthreads();
        if (tid < H) {
            float r3 = 0.f, r4 = 0.f, rc = 0.f;
#pragma unroll
            for (int sl = 0; sl < 8; ++sl) {
                r3 += sRed[sl][0][tid];
                r4 += sRed[sl][1][tid];
                rc += sRed[sl][2][tid];
            }
            u3g[tid] = r3;
            u4g[tid] = r4;
            ccg[tid] = rc + b_gate[tid];
        }
    }
}

// ---------------------------------------------------------------------------
// Kernel 2: main — deferred softmax (no max: logits bounded |lg| <~ 2),
// 16 fully independent j-iterations per wave, no loop-carried chain.
// ---------------------------------------------------------------------------
__global__ __launch_bounds__(BLOCK) void gat_main(
    const float* __restrict__ ha, const float* __restrict__ hg,
    const float* __restrict__ W_gat, const float* __restrict__ gat_bias,
    const float* __restrict__ A1, const float* __restrict__ A2,
    const float* __restrict__ G2,
    const float* __restrict__ u3a, const float* __restrict__ u4a,
    const float* __restrict__ cca,
    const float* __restrict__ vsrc, const float* __restrict__ vdst,
    const float* __restrict__ goal, const float* __restrict__ action,
    float* __restrict__ out)
{
    const int i    = blockIdx.x;
    const int tid  = threadIdx.x;
    const int wid  = tid >> 6;
    const int lane = tid & 63;
    const int f0   = lane * 2;

    __shared__ float2 sAct[N];
    __shared__ float2 sGoal[N];
    __shared__ float  sBase[N];
    __shared__ float2 sD[M];             // (d_ij, d_ji) per j
    __shared__ float  sW[WAVES][K][H];   // 32 KB
    __shared__ float  sL[WAVES][K];
    __shared__ float  sWfin[K][H];
    __shared__ float  sPart[8][H];

    // ---- issue per-lane constant loads first (latency hides under staging)
    const float2 a1v = *(const float2*)&A1[i * H + f0];
    const float2 haI = *(const float2*)&ha[i * H + f0];
    const float2 hgI = *(const float2*)&hg[i * H + f0];
    const float2 g2v = *(const float2*)&G2[i * H + f0];
    const float2 u3  = *(const float2*)&u3a[f0];
    const float2 u4  = *(const float2*)&u4a[f0];
    const float2 cc  = *(const float2*)&cca[f0];
    const float2 vd0 = *(const float2*)&vdst[0 * H + f0];
    const float2 vd1 = *(const float2*)&vdst[1 * H + f0];
    const float2 vd2 = *(const float2*)&vdst[2 * H + f0];
    const float2 vd3 = *(const float2*)&vdst[3 * H + f0];
    const float2 vs0 = *(const float2*)&vsrc[0 * H + f0];
    const float2 vs1 = *(const float2*)&vsrc[1 * H + f0];
    const float2 vs2 = *(const float2*)&vsrc[2 * H + f0];
    const float2 vs3 = *(const float2*)&vsrc[3 * H + f0];

    // geometry staging + bit-exact base recompute
    for (int t = tid; t < N; t += BLOCK) {
        float2 a = ((const float2*)action)[t];
        float2 g = ((const float2*)goal)[t];
        sAct[t]  = a;
        sGoal[t] = g;
        float dx = __fsub_rn(a.x, g.x), dy = __fsub_rn(a.y, g.y);
        sBase[t] = __fsqrt_rn(__fadd_rn(__fmul_rn(dx, dx), __fmul_rn(dy, dy)));
    }
    __syncthreads();

    // distance pass: one (i,j) pair per thread (bit-identical pairdist)
    if (tid < M) {
        const int j = tid;
        float dij = 0.f, dji = 0.f;
        if (j != i && j != N) {
            const float2 aI = sAct[i], gI = sGoal[i];
            const float2 aJ = sAct[j], gJ = sGoal[j];
            if (i < j)
                pairdist(aI.x, aI.y, aJ.x, aJ.y, gI.x, gI.y, gJ.x, gJ.y,
                         sBase[i], sBase[j], dij, dji);
            else
                pairdist(aJ.x, aJ.y, aI.x, aI.y, gJ.x, gJ.y, gI.x, gI.y,
                         sBase[j], sBase[i], dji, dij);
        }
        sD[j] = make_float2(dij, dji);
    }

    // sc[k] = ha[i] . v_src[k]; lane l holds k = l&3
    const float scOwn = kbutterfly(haI.x * vs0.x + haI.y * vs0.y,
                                   haI.x * vs1.x + haI.y * vs1.y,
                                   haI.x * vs2.x + haI.y * vs2.y,
                                   haI.x * vs3.x + haI.y * vs3.y, lane);

    const float2 a1cc = make_float2(a1v.x + cc.x, a1v.y + cc.y);
    const float baseI = sBase[i];
    __syncthreads();   // sD ready

    // deferred softmax: p = exp(lg) directly (logits bounded, no overflow).
    // l_ on lane l accumulates p[k = l&3]; w accumulators per-f per-k.
    float l_ = 0.f;
    float w00 = 0.f, w01 = 0.f, w02 = 0.f, w03 = 0.f;
    float w10 = 0.f, w11 = 0.f, w12 = 0.f, w13 = 0.f;

#pragma unroll
    for (int t = 0; t < 16; ++t) {
        const int jj = wid + 16 * t;
        const float2 a2 = *(const float2*)&A2[jj * H + f0];
        const float2 hj = *(const float2*)&ha[jj * H + f0];
        const float2 d  = sD[jj];
        float tx = a1cc.x + a2.x + d.x * u3.x + d.y * u4.x;
        float ty = a1cc.y + a2.y + d.x * u3.y + d.y * u4.y;
        float2 g = make_float2(hj.x * sigm(tx), hj.y * sigm(ty));
        if (jj == i) g = haI;          // diagonal: ungated ha[i]

        float q0 = g.x * vd0.x + g.y * vd0.y;
        float q1 = g.x * vd1.x + g.y * vd1.y;
        float q2 = g.x * vd2.x + g.y * vd2.y;
        float q3 = g.x * vd3.x + g.y * vd3.y;
        float e  = kbutterfly(q0, q1, q2, q3, lane);

        float lg = scOwn + e;
        lg = (lg >= 0.f) ? lg : 0.2f * lg;     // leaky_relu
        const float p = __expf(lg);
        l_ += p;

        const float p0 = readlane_f(p, 0), p1 = readlane_f(p, 1);
        const float p2 = readlane_f(p, 2), p3 = readlane_f(p, 3);
        w00 += p0 * g.x;  w10 += p0 * g.y;
        w01 += p1 * g.x;  w11 += p1 * g.y;
        w02 += p2 * g.x;  w12 += p2 * g.y;
        w03 += p3 * g.x;  w13 += p3 * g.y;
    }

    // tail: wave 0 handles j = N (goal row)
    if (wid == 0) {
        float tx = a1cc.x + g2v.x + baseI * (u3.x + u4.x);
        float ty = a1cc.y + g2v.y + baseI * (u3.y + u4.y);
        float2 g = make_float2(hgI.x * sigm(tx), hgI.y * sigm(ty));

        float q0 = g.x * vd0.x + g.y * vd0.y;
        float q1 = g.x * vd1.x + g.y * vd1.y;
        float q2 = g.x * vd2.x + g.y * vd2.y;
        float q3 = g.x * vd3.x + g.y * vd3.y;
        float e  = kbutterfly(q0, q1, q2, q3, lane);

        float lg = scOwn + e;
        lg = (lg >= 0.f) ? lg : 0.2f * lg;
        const float p = __expf(lg);
        l_ += p;

        const float p0 = readlane_f(p, 0), p1 = readlane_f(p, 1);
        const float p2 = readlane_f(p, 2), p3 = readlane_f(p, 3);
        w00 += p0 * g.x;  w10 += p0 * g.y;
        w01 += p1 * g.x;  w11 += p1 * g.y;
        w02 += p2 * g.x;  w12 += p2 * g.y;
        w03 += p3 * g.x;  w13 += p3 * g.y;
    }

    // dump per-wave partials
    *(float2*)&sW[wid][0][f0] = make_float2(w00, w10);
    *(float2*)&sW[wid][1][f0] = make_float2(w01, w11);
    *(float2*)&sW[wid][2][f0] = make_float2(w02, w12);
    *(float2*)&sW[wid][3][f0] = make_float2(w03, w13);
    if (lane < K) sL[wid][lane] = l_;   // lane l holds Σ_j p[j][l&3]
    __syncthreads();

    // merge 16 wave partials; normalize by L[k] = Σ_w sL[w][k]
    if (tid < K * H) {
        const int k = tid >> 7;
        const int f = tid & (H - 1);
        float W = 0.f;
#pragma unroll
        for (int w = 0; w < WAVES; ++w) W += sW[w][k][f];
        float L = 0.f;
#pragma unroll
        for (int w = 0; w < WAVES; ++w) L += sL[w][k];
        sWfin[k][f] = W / L;
    }
    __syncthreads();

    // epilogue: out[f] = elu( 0.25 * sum_k wfin[k] @ W_gat[k][:,f] + bias[f] )
    {
        const int f = tid & (H - 1);
        const int s = tid >> 7;   // 0..7 -> g-slice of 16
        float acc = 0.0f;
#pragma unroll
        for (int k = 0; k < K; ++k) {
            const int g0 = s * 16;
#pragma unroll
            for (int g = 0; g < 16; ++g)
                acc += sWfin[k][g0 + g] * W_gat[(k * H + g0 + g) * H + f];
        }
        sPart[s][f] = acc;
    }
    __syncthreads();

    if (tid < H) {
        float acc = 0.0f;
#pragma unroll
        for (int s = 0; s < 8; ++s) acc += sPart[s][tid];
        float val = 0.25f * acc + gat_bias[tid];
        out[i * H + tid] = (val > 0.0f) ? val : expm1f(val);
    }
}

// ---------------------------------------------------------------------------
extern "C" void kernel_launch(void* const* d_in, const int* in_sizes, int n_in,
                              void* d_out, int out_size, void* d_ws, size_t ws_size,
                              hipStream_t stream)
{
    const float* ha       = (const float*)d_in[0];
    const float* hg       = (const float*)d_in[1];
    const float* goal     = (const float*)d_in[2];
    const float* action   = (const float*)d_in[3];
    const float* W_emb    = (const float*)d_in[4];
    const float* b_emb    = (const float*)d_in[5];
    const float* W_gate   = (const float*)d_in[6];
    const float* b_gate   = (const float*)d_in[7];
    const float* W_gat    = (const float*)d_in[8];
    const float* a_src    = (const float*)d_in[9];
    const float* a_dst    = (const float*)d_in[10];
    const float* gat_bias = (const float*)d_in[11];

    float* ws  = (float*)d_ws;
    float* A1  = ws;                 // N*H
    float* A2  = A1 + N * H;         // N*H
    float* G2  = A2 + N * H;         // N*H
    float* u3  = G2 + N * H;         // H
    float* u4  = u3 + H;             // H
    float* cc  = u4 + H;             // H
    float* vs  = cc + H;             // K*H
    float* vd  = vs + K * H;         // K*H

    hipLaunchKernelGGL(gat_pre, dim3(N), dim3(BLOCK), 0, stream,
                       ha, hg, W_emb, b_emb, W_gate, b_gate,
                       W_gat, a_src, a_dst,
                       A1, A2, G2, u3, u4, cc, vs, vd);

    hipLaunchKernelGGL(gat_main, dim3(N), dim3(BLOCK), 0, stream,
                       ha, hg, W_gat, gat_bias,
                       A1, A2, G2, u3, u4, cc, vs, vd,
                       goal, action, (float*)d_out);
}

// Round 7
// 26.497 us; speedup vs baseline: 1.0744x; 1.0744x over previous
//
#include <hip/hip_runtime.h>
#include <math.h>

#define N 256
#define H 128
#define E 64
#define K 4
#define M (N + 1)
#define WAVES 16
#define BLOCK 1024

// ---------------------------------------------------------------------------
// helpers
// ---------------------------------------------------------------------------
__device__ __forceinline__ float sigm(float x) {
    return __fdividef(1.0f, 1.0f + __expf(-x));
}

__device__ __forceinline__ float wave_sum(float v) {
#pragma unroll
    for (int d = 1; d < 64; d <<= 1) v += __shfl_xor(v, d, 64);
    return v;
}

__device__ __forceinline__ float readlane_f(float v, int l) {
    return __uint_as_float(__builtin_amdgcn_readlane(__float_as_uint(v), l));
}

// full k-transposed butterfly: lane l ends with wave_sum(q_{l&3})
__device__ __forceinline__ float kbutterfly(float q0, float q1, float q2, float q3,
                                            int lane) {
    const bool b1 = lane & 1;
    const bool b2 = lane & 2;
    float aA = b1 ? q1 : q0, aB = b1 ? q0 : q1;
    aA += __shfl_xor(aB, 1, 64);
    float cA = b1 ? q3 : q2, cB = b1 ? q2 : q3;
    cA += __shfl_xor(cB, 1, 64);
    float eA = b2 ? cA : aA, eB = b2 ? aA : cA;
    eA += __shfl_xor(eB, 2, 64);
#pragma unroll
    for (int d = 4; d < 64; d <<= 1) eA += __shfl_xor(eA, d, 64);
    return eA;
}

// Bit-exact replication of cal_dist's per-pair math (numpy fp32, no FMA
// contraction). Roles: r = row idx, c = col idx, r < c. Returns d[r][c], d[c][r].
__device__ __forceinline__ void pairdist(
    float a1x, float a1y, float a2x, float a2y,
    float g1x, float g1y, float g2x, float g2y,
    float baseR, float baseC, float& d_rc, float& d_cr)
{
    float t  = __fmul_rn(__fsub_rn(a1y, a2y), __fsub_rn(g1x, g2x));
    float dn = -t;  // (a1x-a1x)*(...) == 0 exactly
    float ca = __fsub_rn(__fmul_rn(a1x, a2y), __fmul_rn(a1y, a2x));
    float gt = __fsub_rn(__fmul_rn(g1x, g2y), __fmul_rn(g1x, g2x));  // ref bug kept
    float n1 = __fsub_rn(__fmul_rn(ca, __fsub_rn(g1x, g2x)),
                         __fmul_rn(__fsub_rn(a1x, a2x), gt));
    float n2 = __fsub_rn(__fmul_rn(ca, __fsub_rn(g1y, g2y)),
                         __fmul_rn(__fsub_rn(a1y, a2x), gt));        // ref bug kept
    float safe = (dn == 0.0f) ? 1.0f : dn;
    float p1 = __fdiv_rn(n1, safe);
    float p2 = __fdiv_rn(n2, safe);
    bool cond = (dn != 0.0f) &&
                (__fmul_rn(__fsub_rn(a1x, p1), __fsub_rn(p1, g1x)) > 0.0f);
    float dx1 = __fsub_rn(a1x, p1), dy1 = __fsub_rn(a1y, p2);
    float d1p = __fsqrt_rn(__fadd_rn(__fmul_rn(dx1, dx1), __fmul_rn(dy1, dy1)));
    float dx2 = __fsub_rn(a2x, p1), dy2 = __fsub_rn(a2y, p2);
    float d2p = __fsqrt_rn(__fadd_rn(__fmul_rn(dx2, dx2), __fmul_rn(dy2, dy2)));
    d_rc = cond ? d1p : baseR;
    d_cr = cond ? d2p : baseC;
}

// ---------------------------------------------------------------------------
// Kernel 1: precompute, 256 uniform blocks x 1024 threads.
//   every b  : A1[b], G2[b], pk[b] = packed(A2[b], ha[b])  (8 g-slices)
//   waves14/15: 2 vsrc/vdst (k,f)-pairs per block (512 total, coalesced)
//   b<2 w2-9 : u3/u4/cc e-slices (same summation order as before)
// ---------------------------------------------------------------------------
__global__ __launch_bounds__(BLOCK) void gat_pre(
    const float* __restrict__ ha, const float* __restrict__ hg,
    const float* __restrict__ W_emb, const float* __restrict__ b_emb,
    const float* __restrict__ W_gate, const float* __restrict__ b_gate,
    const float* __restrict__ W_gat, const float* __restrict__ a_src,
    const float* __restrict__ a_dst,
    float* __restrict__ A1, float* __restrict__ G2,
    float* __restrict__ u3g, float* __restrict__ u4g, float* __restrict__ ccg,
    float* __restrict__ vsrc, float* __restrict__ vdst,
    float4* __restrict__ pk)
{
    const int b    = blockIdx.x;
    const int tid  = threadIdx.x;
    const int wid  = tid >> 6;
    const int lane = tid & 63;

    __shared__ float sRed[8][3][H];
    __shared__ float sA2[H];
    __shared__ float sU[8][3][64];

    // phase 1: A-slices (all waves)
    {
        const int f  = tid & (H - 1);
        const int sl = tid >> 7;
        const int g0 = sl * 16;
        float s1 = 0.f, s2 = 0.f, s3 = 0.f;
#pragma unroll
        for (int g = 0; g < 16; ++g) {
            const int gg = g0 + g;
            float w1 = W_gate[gg * H + f];
            float w2 = W_gate[(H + gg) * H + f];
            float av = ha[b * H + gg];
            float gv = hg[b * H + gg];
            s1 += av * w1;
            s2 += av * w2;
            s3 += gv * w2;
        }
        sRed[sl][0][f] = s1;
        sRed[sl][1][f] = s2;
        sRed[sl][2][f] = s3;
    }

    // distributed vsrc/vdst: waves 14,15 handle pairs p = 2b, 2b+1
    if (wid >= 14) {
        const int p = 2 * b + (wid - 14);       // 0..511
        const int k = p >> 7;
        const int f = p & (H - 1);
        const float2 w2 = ((const float2*)&W_gat[(k * H + f) * H])[lane];
        const float2 as2 = ((const float2*)&a_src[k * H])[lane];
        const float2 ad2 = ((const float2*)&a_dst[k * H])[lane];
        float vsv = wave_sum(w2.x * as2.x + w2.y * as2.y);
        float vdv = wave_sum(w2.x * ad2.x + w2.y * ad2.y);
        if (lane == 0) { vsrc[k * H + f] = vsv; vdst[k * H + f] = vdv; }
    }

    // distributed u3/u4/cc partials: blocks 0,1 / waves 2..9, e-slice of 8
    if (b < 2 && wid >= 2 && wid < 10) {
        const int sl = wid - 2;
        const int f  = (b << 6) | lane;
        float s3 = 0.f, s4 = 0.f, scc = 0.f;
#pragma unroll
        for (int e0 = 0; e0 < 8; ++e0) {
            const int e = sl * 8 + e0;
            float w3 = W_gate[(2 * H + e) * H + f];
            float w4 = W_gate[(2 * H + E + e) * H + f];
            float we = W_emb[e], be = b_emb[e];
            s3  += we * w3;
            s4  += we * w4;
            scc += be * (w3 + w4);
        }
        sU[sl][0][lane] = s3;
        sU[sl][1][lane] = s4;
        sU[sl][2][lane] = scc;
    }
    __syncthreads();

    // phase 2: reduce A-slices
    if (tid < H) {
        float r1 = 0.f, r2 = 0.f, r3 = 0.f;
#pragma unroll
        for (int sl = 0; sl < 8; ++sl) {
            r1 += sRed[sl][0][tid];
            r2 += sRed[sl][1][tid];
            r3 += sRed[sl][2][tid];
        }
        A1[b * H + tid] = r1;
        G2[b * H + tid] = r3;
        sA2[tid] = r2;
    }
    __syncthreads();

    // phase 3: pack (A2, ha) -> pk; finish u-vectors
    if (tid < 64) {
        const float2 h2 = ((const float2*)&ha[b * H])[tid];
        pk[(b << 6) | tid] = make_float4(sA2[2 * tid], sA2[2 * tid + 1], h2.x, h2.y);
    }
    if (b < 2 && tid < 192) {
        const int c  = tid >> 6;
        const int fl = tid & 63;
        float r = 0.f;
#pragma unroll
        for (int w = 0; w < 8; ++w) r += sU[w][c][fl];
        const int f = (b << 6) | fl;
        if (c == 0)      u3g[f] = r;
        else if (c == 1) u4g[f] = r;
        else             ccg[f] = r + b_gate[f];
    }
}

// ---------------------------------------------------------------------------
// Kernel 2: main — deferred softmax (logits bounded), 16 independent
// j-iterations per wave, single packed float4 stream in the loop.
// ---------------------------------------------------------------------------
__global__ __launch_bounds__(BLOCK) void gat_main(
    const float* __restrict__ ha, const float* __restrict__ hg,
    const float* __restrict__ W_gat, const float* __restrict__ gat_bias,
    const float* __restrict__ A1, const float* __restrict__ G2,
    const float* __restrict__ u3a, const float* __restrict__ u4a,
    const float* __restrict__ cca,
    const float* __restrict__ vsrc, const float* __restrict__ vdst,
    const float4* __restrict__ pk,
    const float* __restrict__ goal, const float* __restrict__ action,
    float* __restrict__ out)
{
    const int i    = blockIdx.x;
    const int tid  = threadIdx.x;
    const int wid  = tid >> 6;
    const int lane = tid & 63;
    const int f0   = lane * 2;

    __shared__ float2 sAct[N];
    __shared__ float2 sGoal[N];
    __shared__ float  sBase[N];
    __shared__ float2 sD[M];             // (d_ij, d_ji) per j
    __shared__ float  sW[WAVES][K][H];   // 32 KB
    __shared__ float  sL[WAVES][K];
    __shared__ float  sWfin[K][H];
    __shared__ float  sPart[8][H];

    // ---- issue per-lane constant loads first (latency hides under staging)
    const float2 a1v = *(const float2*)&A1[i * H + f0];
    const float2 haI = *(const float2*)&ha[i * H + f0];
    const float2 hgI = *(const float2*)&hg[i * H + f0];
    const float2 g2v = *(const float2*)&G2[i * H + f0];
    const float2 u3  = *(const float2*)&u3a[f0];
    const float2 u4  = *(const float2*)&u4a[f0];
    const float2 cc  = *(const float2*)&cca[f0];
    const float2 vd0 = *(const float2*)&vdst[0 * H + f0];
    const float2 vd1 = *(const float2*)&vdst[1 * H + f0];
    const float2 vd2 = *(const float2*)&vdst[2 * H + f0];
    const float2 vd3 = *(const float2*)&vdst[3 * H + f0];
    const float2 vs0 = *(const float2*)&vsrc[0 * H + f0];
    const float2 vs1 = *(const float2*)&vsrc[1 * H + f0];
    const float2 vs2 = *(const float2*)&vsrc[2 * H + f0];
    const float2 vs3 = *(const float2*)&vsrc[3 * H + f0];

    // geometry staging + bit-exact base recompute
    if (tid < N) {
        float2 a = ((const float2*)action)[tid];
        float2 g = ((const float2*)goal)[tid];
        sAct[tid]  = a;
        sGoal[tid] = g;
        float dx = __fsub_rn(a.x, g.x), dy = __fsub_rn(a.y, g.y);
        sBase[tid] = __fsqrt_rn(__fadd_rn(__fmul_rn(dx, dx), __fmul_rn(dy, dy)));
    }
    __syncthreads();

    // distance pass: one (i,j) pair per thread (bit-identical pairdist)
    if (tid < M) {
        const int j = tid;
        float dij = 0.f, dji = 0.f;
        if (j != i && j != N) {
            const float2 aI = sAct[i], gI = sGoal[i];
            const float2 aJ = sAct[j], gJ = sGoal[j];
            if (i < j)
                pairdist(aI.x, aI.y, aJ.x, aJ.y, gI.x, gI.y, gJ.x, gJ.y,
                         sBase[i], sBase[j], dij, dji);
            else
                pairdist(aJ.x, aJ.y, aI.x, aI.y, gJ.x, gJ.y, gI.x, gI.y,
                         sBase[j], sBase[i], dji, dij);
        }
        sD[j] = make_float2(dij, dji);
    }

    // sc[k] = ha[i] . v_src[k]; lane l holds k = l&3
    const float scOwn = kbutterfly(haI.x * vs0.x + haI.y * vs0.y,
                                   haI.x * vs1.x + haI.y * vs1.y,
                                   haI.x * vs2.x + haI.y * vs2.y,
                                   haI.x * vs3.x + haI.y * vs3.y, lane);

    const float2 a1cc = make_float2(a1v.x + cc.x, a1v.y + cc.y);
    const float baseI = sBase[i];
    __syncthreads();   // sD ready

    // deferred softmax: p = exp(lg) directly (logits bounded, no overflow).
    float l_ = 0.f;
    float w00 = 0.f, w01 = 0.f, w02 = 0.f, w03 = 0.f;
    float w10 = 0.f, w11 = 0.f, w12 = 0.f, w13 = 0.f;

#pragma unroll
    for (int t = 0; t < 16; ++t) {
        const int jj = wid + 16 * t;
        const float4 ph = pk[(jj << 6) | lane];   // {A2x, A2y, hax, hay}
        const float2 d  = sD[jj];
        float tx = a1cc.x + ph.x + d.x * u3.x + d.y * u4.x;
        float ty = a1cc.y + ph.y + d.x * u3.y + d.y * u4.y;
        float2 g = make_float2(ph.z * sigm(tx), ph.w * sigm(ty));
        if (jj == i) g = haI;          // diagonal: ungated ha[i]

        float q0 = g.x * vd0.x + g.y * vd0.y;
        float q1 = g.x * vd1.x + g.y * vd1.y;
        float q2 = g.x * vd2.x + g.y * vd2.y;
        float q3 = g.x * vd3.x + g.y * vd3.y;
        float e  = kbutterfly(q0, q1, q2, q3, lane);

        float lg = scOwn + e;
        lg = (lg >= 0.f) ? lg : 0.2f * lg;     // leaky_relu
        const float p = __expf(lg);
        l_ += p;

        const float p0 = readlane_f(p, 0), p1 = readlane_f(p, 1);
        const float p2 = readlane_f(p, 2), p3 = readlane_f(p, 3);
        w00 += p0 * g.x;  w10 += p0 * g.y;
        w01 += p1 * g.x;  w11 += p1 * g.y;
        w02 += p2 * g.x;  w12 += p2 * g.y;
        w03 += p3 * g.x;  w13 += p3 * g.y;
    }

    // tail: wave 0 handles j = N (goal row)
    if (wid == 0) {
        float tx = a1cc.x + g2v.x + baseI * (u3.x + u4.x);
        float ty = a1cc.y + g2v.y + baseI * (u3.y + u4.y);
        float2 g = make_float2(hgI.x * sigm(tx), hgI.y * sigm(ty));

        float q0 = g.x * vd0.x + g.y * vd0.y;
        float q1 = g.x * vd1.x + g.y * vd1.y;
        float q2 = g.x * vd2.x + g.y * vd2.y;
        float q3 = g.x * vd3.x + g.y * vd3.y;
        float e  = kbutterfly(q0, q1, q2, q3, lane);

        float lg = scOwn + e;
        lg = (lg >= 0.f) ? lg : 0.2f * lg;
        const float p = __expf(lg);
        l_ += p;

        const float p0 = readlane_f(p, 0), p1 = readlane_f(p, 1);
        const float p2 = readlane_f(p, 2), p3 = readlane_f(p, 3);
        w00 += p0 * g.x;  w10 += p0 * g.y;
        w01 += p1 * g.x;  w11 += p1 * g.y;
        w02 += p2 * g.x;  w12 += p2 * g.y;
        w03 += p3 * g.x;  w13 += p3 * g.y;
    }

    // dump per-wave partials
    *(float2*)&sW[wid][0][f0] = make_float2(w00, w10);
    *(float2*)&sW[wid][1][f0] = make_float2(w01, w11);
    *(float2*)&sW[wid][2][f0] = make_float2(w02, w12);
    *(float2*)&sW[wid][3][f0] = make_float2(w03, w13);
    if (lane < K) sL[wid][lane] = l_;   // lane l holds Σ_j p[j][l&3]
    __syncthreads();

    // merge 16 wave partials; normalize by L[k] = Σ_w sL[w][k]
    if (tid < K * H) {
        const int k = tid >> 7;
        const int f = tid & (H - 1);
        float W = 0.f;
#pragma unroll
        for (int w = 0; w < WAVES; ++w) W += sW[w][k][f];
        float L = 0.f;
#pragma unroll
        for (int w = 0; w < WAVES; ++w) L += sL[w][k];
        sWfin[k][f] = W / L;
    }
    __syncthreads();

    // epilogue: out[f] = elu( 0.25 * sum_k wfin[k] @ W_gat[k][:,f] + bias[f] )
    {
        const int f = tid & (H - 1);
        const int s = tid >> 7;   // 0..7 -> g-slice of 16
        float acc = 0.0f;
#pragma unroll
        for (int k = 0; k < K; ++k) {
            const int g0 = s * 16;
#pragma unroll
            for (int g = 0; g < 16; ++g)
                acc += sWfin[k][g0 + g] * W_gat[(k * H + g0 + g) * H + f];
        }
        sPart[s][f] = acc;
    }
    __syncthreads();

    if (tid < H) {
        float acc = 0.0f;
#pragma unroll
        for (int s = 0; s < 8; ++s) acc += sPart[s][tid];
        float val = 0.25f * acc + gat_bias[tid];
        out[i * H + tid] = (val > 0.0f) ? val : expm1f(val);
    }
}

// ---------------------------------------------------------------------------
extern "C" void kernel_launch(void* const* d_in, const int* in_sizes, int n_in,
                              void* d_out, int out_size, void* d_ws, size_t ws_size,
                              hipStream_t stream)
{
    const float* ha       = (const float*)d_in[0];
    const float* hg       = (const float*)d_in[1];
    const float* goal     = (const float*)d_in[2];
    const float* action   = (const float*)d_in[3];
    const float* W_emb    = (const float*)d_in[4];
    const float* b_emb    = (const float*)d_in[5];
    const float* W_gate   = (const float*)d_in[6];
    const float* b_gate   = (const float*)d_in[7];
    const float* W_gat    = (const float*)d_in[8];
    const float* a_src    = (const float*)d_in[9];
    const float* a_dst    = (const float*)d_in[10];
    const float* gat_bias = (const float*)d_in[11];

    float* ws  = (float*)d_ws;
    float*  A1 = ws;                  // N*H           (offset 0)
    float*  G2 = A1 + N * H;          // N*H           (32768)
    float*  u3 = G2 + N * H;          // H             (65536)
    float*  u4 = u3 + H;              // H             (65664)
    float*  cc = u4 + H;              // H             (65792)
    float*  vs = cc + H;              // K*H           (65920)
    float*  vd = vs + K * H;          // K*H           (66432)
    float4* pk = (float4*)(vd + K * H); // N*64 float4 (66944, 16B-aligned)

    hipLaunchKernelGGL(gat_pre, dim3(N), dim3(BLOCK), 0, stream,
                       ha, hg, W_emb, b_emb, W_gate, b_gate,
                       W_gat, a_src, a_dst,
                       A1, G2, u3, u4, cc, vs, vd, pk);

    hipLaunchKernelGGL(gat_main, dim3(N), dim3(BLOCK), 0, stream,
                       ha, hg, W_gat, gat_bias,
                       A1, G2, u3, u4, cc, vs, vd, pk,
                       goal, action, (float*)d_out);
}